// Round 2
// baseline (89.181 us; speedup 1.0000x reference)
//
#include <hip/hip_runtime.h>
#include <hip/hip_bf16.h>

#define NB 20000      // batch
#define KN 16         // neighbors
#define D 256
#define KDIM 512      // 2*D
#define MDIM 512      // 2*OUT stacked

typedef __bf16 bf16x8 __attribute__((ext_vector_type(8)));
typedef float f32x4 __attribute__((ext_vector_type(4)));

__device__ inline unsigned short f2bf(float f) {
    union { float f; unsigned int u; } a; a.f = f;
    unsigned int u = a.u;
    unsigned int r = (u + 0x7FFFu + ((u >> 16) & 1u)) >> 16;   // RNE
    return (unsigned short)r;
}

// --- kernel 1: W1||W2 f32 -> bf16, stacked [512][512] ---
__global__ __launch_bounds__(256) void convW_kernel(
        const float* __restrict__ W1, const float* __restrict__ W2,
        unsigned short* __restrict__ Wc) {
    int i = blockIdx.x * 256 + threadIdx.x;          // 65536 float4 chunks
    float4 v = (i < 32768) ? reinterpret_cast<const float4*>(W1)[i]
                           : reinterpret_cast<const float4*>(W2)[i - 32768];
    ushort4 o;
    o.x = f2bf(v.x); o.y = f2bf(v.y); o.z = f2bf(v.z); o.w = f2bf(v.w);
    reinterpret_cast<ushort4*>(Wc)[i] = o;
}

// --- kernel 2: gather + mean aggregate, pack bf16 combined [20000][512] ---
__global__ __launch_bounds__(256) void agg_kernel(
        const int* __restrict__ nodes, const int* __restrict__ neigh,
        const float* __restrict__ feat, unsigned short* __restrict__ comb) {
    int w = threadIdx.x >> 6;
    int lane = threadIdx.x & 63;
    int b = blockIdx.x * 4 + w;                      // grid = 5000 -> b < 20000
    const float4* f4 = reinterpret_cast<const float4*>(feat);  // row = 64 float4

    int node = nodes[b];
    float4 s = f4[node * 64 + lane];

    float4 m; m.x = 0.f; m.y = 0.f; m.z = 0.f; m.w = 0.f;
    #pragma unroll
    for (int k = 0; k < KN; ++k) {
        int idx = neigh[b * KN + k];
        float4 v = f4[idx * 64 + lane];
        m.x += v.x; m.y += v.y; m.z += v.z; m.w += v.w;
    }
    const float inv = 1.0f / 16.0f;

    ushort4 sv; sv.x = f2bf(s.x); sv.y = f2bf(s.y); sv.z = f2bf(s.z); sv.w = f2bf(s.w);
    ushort4 mv; mv.x = f2bf(m.x * inv); mv.y = f2bf(m.y * inv);
    mv.z = f2bf(m.z * inv); mv.w = f2bf(m.w * inv);

    unsigned short* row = comb + (size_t)b * KDIM;
    *reinterpret_cast<ushort4*>(row + lane * 4) = sv;          // self  [0,256)
    *reinterpret_cast<ushort4*>(row + D + lane * 4) = mv;      // mean  [256,512)
}

// --- kernel 3: out[m][n] = relu(sum_k Wc[m][k] * comb[n][k]), f32 out ---
#define BM 128
#define BN 128
#define BK 32
#define LDK 40   // padded LDS row (elems); 80B stride, 16B-aligned

__global__ __launch_bounds__(256) void gemm_kernel(
        const unsigned short* __restrict__ Wc,    // [512][512] bf16
        const unsigned short* __restrict__ Cb,    // [20000][512] bf16
        float* __restrict__ out) {                // [512][20000] f32
    __shared__ __align__(16) unsigned short As[BM * LDK];
    __shared__ __align__(16) unsigned short Bs[BN * LDK];

    int tid = threadIdx.x;
    int lane = tid & 63;
    int wid = tid >> 6;
    int wm = wid >> 1, wn = wid & 1;              // 2x2 wave grid, 64x64 each
    int mBase = blockIdx.y * BM;
    int nBase = blockIdx.x * BN;

    f32x4 acc[4][4] = {};

    int srow = tid >> 2;                          // 0..63
    int scol = (tid & 3) * 8;                     // 0,8,16,24

    for (int k0 = 0; k0 < KDIM; k0 += BK) {
        #pragma unroll
        for (int h = 0; h < 2; ++h) {
            int r = srow + h * 64;
            uint4 va = *reinterpret_cast<const uint4*>(
                Wc + (size_t)(mBase + r) * KDIM + k0 + scol);
            *reinterpret_cast<uint4*>(&As[r * LDK + scol]) = va;
            int gb = nBase + r;
            uint4 vb;
            if (gb < NB) vb = *reinterpret_cast<const uint4*>(
                    Cb + (size_t)gb * KDIM + k0 + scol);
            else { vb.x = 0; vb.y = 0; vb.z = 0; vb.w = 0; }
            *reinterpret_cast<uint4*>(&Bs[r * LDK + scol]) = vb;
        }
        __syncthreads();

        int kq = (lane >> 4) * 8;                 // k sub-block per lane group
        int rl = lane & 15;
        bf16x8 af[4], bfr[4];
        #pragma unroll
        for (int i = 0; i < 4; ++i) {
            af[i]  = *reinterpret_cast<const bf16x8*>(&As[(wm * 64 + i * 16 + rl) * LDK + kq]);
            bfr[i] = *reinterpret_cast<const bf16x8*>(&Bs[(wn * 64 + i * 16 + rl) * LDK + kq]);
        }
        #pragma unroll
        for (int i = 0; i < 4; ++i)
            #pragma unroll
            for (int j = 0; j < 4; ++j)
                acc[i][j] = __builtin_amdgcn_mfma_f32_16x16x32_bf16(
                    af[i], bfr[j], acc[i][j], 0, 0, 0);
        __syncthreads();
    }

    // epilogue: C/D layout col=lane&15, row=(lane>>4)*4+reg (m89-verified)
    int col = lane & 15;
    int rq = (lane >> 4) * 4;
    #pragma unroll
    for (int i = 0; i < 4; ++i) {
        #pragma unroll
        for (int j = 0; j < 4; ++j) {
            int n = nBase + wn * 64 + j * 16 + col;
            if (n < NB) {
                int mRow = mBase + wm * 64 + i * 16 + rq;
                #pragma unroll
                for (int r = 0; r < 4; ++r) {
                    float v = acc[i][j][r];
                    out[(size_t)(mRow + r) * NB + n] = v > 0.f ? v : 0.f;
                }
            }
        }
    }
}

extern "C" void kernel_launch(void* const* d_in, const int* in_sizes, int n_in,
                              void* d_out, int out_size, void* d_ws, size_t ws_size,
                              hipStream_t stream) {
    const int*   nodes = (const int*)d_in[0];
    const int*   neigh = (const int*)d_in[1];
    const float* feat  = (const float*)d_in[2];
    const float* W1    = (const float*)d_in[3];
    const float* W2    = (const float*)d_in[4];
    float* out = (float*)d_out;

    unsigned short* Wc   = (unsigned short*)d_ws;                       // 512*512*2 = 512KB
    unsigned short* comb = (unsigned short*)((char*)d_ws + MDIM * KDIM * 2); // 20.5MB

    convW_kernel<<<256, 256, 0, stream>>>(W1, W2, Wc);
    agg_kernel<<<NB / 4, 256, 0, stream>>>(nodes, neigh, feat, comb);
    gemm_kernel<<<dim3((NB + BN - 1) / BN, MDIM / BM), 256, 0, stream>>>(Wc, comb, out);
}

// Round 3
// 87.687 us; speedup vs baseline: 1.0170x; 1.0170x over previous
//
#include <hip/hip_runtime.h>
#include <hip/hip_bf16.h>

#define NB 20000      // batch
#define KN 16         // neighbors
#define D 256
#define KDIM 512      // 2*D
#define MDIM 512      // 2*OUT stacked
#define NTOT 100000   // feature table rows

typedef __bf16 bf16x8 __attribute__((ext_vector_type(8)));
typedef float f32x4 __attribute__((ext_vector_type(4)));

__device__ inline unsigned short f2bf(float f) {
    union { float f; unsigned int u; } a; a.f = f;
    unsigned int u = a.u;
    unsigned int r = (u + 0x7FFFu + ((u >> 16) & 1u)) >> 16;   // RNE
    return (unsigned short)r;
}
__device__ inline float bf2f(unsigned short h) {
    union { unsigned int u; float f; } a; a.u = ((unsigned int)h) << 16;
    return a.f;
}

// --- kernel 0: feature table f32 -> bf16 (streaming), [100000][256] ---
__global__ __launch_bounds__(256) void conv_feat_kernel(
        const float* __restrict__ feat, unsigned short* __restrict__ fb) {
    const long long total = (long long)NTOT * D / 8;   // ushort8 chunks
    long long i = (long long)blockIdx.x * 256 + threadIdx.x;
    const long long stride = (long long)gridDim.x * 256;
    for (; i < total; i += stride) {
        float4 a = reinterpret_cast<const float4*>(feat)[i * 2];
        float4 b = reinterpret_cast<const float4*>(feat)[i * 2 + 1];
        ushort4 lo, hi;
        lo.x = f2bf(a.x); lo.y = f2bf(a.y); lo.z = f2bf(a.z); lo.w = f2bf(a.w);
        hi.x = f2bf(b.x); hi.y = f2bf(b.y); hi.z = f2bf(b.z); hi.w = f2bf(b.w);
        reinterpret_cast<ushort4*>(fb)[i * 2] = lo;
        reinterpret_cast<ushort4*>(fb)[i * 2 + 1] = hi;
    }
}

// --- kernel 1: W1||W2 f32 -> bf16, stacked [512][512] ---
__global__ __launch_bounds__(256) void convW_kernel(
        const float* __restrict__ W1, const float* __restrict__ W2,
        unsigned short* __restrict__ Wc) {
    int i = blockIdx.x * 256 + threadIdx.x;          // 65536 float4 chunks
    float4 v = (i < 32768) ? reinterpret_cast<const float4*>(W1)[i]
                           : reinterpret_cast<const float4*>(W2)[i - 32768];
    ushort4 o;
    o.x = f2bf(v.x); o.y = f2bf(v.y); o.z = f2bf(v.z); o.w = f2bf(v.w);
    reinterpret_cast<ushort4*>(Wc)[i] = o;
}

// --- kernel 2a: gather+mean from bf16 table -> comb bf16 [20000][512] ---
__global__ __launch_bounds__(256) void agg_bf16_kernel(
        const int* __restrict__ nodes, const int* __restrict__ neigh,
        const unsigned short* __restrict__ fb, unsigned short* __restrict__ comb) {
    int w = threadIdx.x >> 6;
    int lane = threadIdx.x & 63;
    int b = blockIdx.x * 4 + w;                      // grid = 5000
    const ushort4* t4 = reinterpret_cast<const ushort4*>(fb);  // row = 64 ushort4

    int node = nodes[b];
    ushort4 sv = t4[(size_t)node * 64 + lane];       // self: passthrough bits

    float m0 = 0.f, m1 = 0.f, m2 = 0.f, m3 = 0.f;
    #pragma unroll
    for (int k = 0; k < KN; ++k) {
        int idx = neigh[b * KN + k];
        ushort4 v = t4[(size_t)idx * 64 + lane];
        m0 += bf2f(v.x); m1 += bf2f(v.y); m2 += bf2f(v.z); m3 += bf2f(v.w);
    }
    const float inv = 1.0f / 16.0f;
    ushort4 mv;
    mv.x = f2bf(m0 * inv); mv.y = f2bf(m1 * inv);
    mv.z = f2bf(m2 * inv); mv.w = f2bf(m3 * inv);

    unsigned short* row = comb + (size_t)b * KDIM;
    *reinterpret_cast<ushort4*>(row + lane * 4) = sv;          // self  [0,256)
    *reinterpret_cast<ushort4*>(row + D + lane * 4) = mv;      // mean  [256,512)
}

// --- kernel 2b: fallback f32 gather (if ws too small for bf16 table) ---
__global__ __launch_bounds__(256) void agg_kernel(
        const int* __restrict__ nodes, const int* __restrict__ neigh,
        const float* __restrict__ feat, unsigned short* __restrict__ comb) {
    int w = threadIdx.x >> 6;
    int lane = threadIdx.x & 63;
    int b = blockIdx.x * 4 + w;
    const float4* f4 = reinterpret_cast<const float4*>(feat);

    int node = nodes[b];
    float4 s = f4[(size_t)node * 64 + lane];

    float4 m; m.x = 0.f; m.y = 0.f; m.z = 0.f; m.w = 0.f;
    #pragma unroll
    for (int k = 0; k < KN; ++k) {
        int idx = neigh[b * KN + k];
        float4 v = f4[(size_t)idx * 64 + lane];
        m.x += v.x; m.y += v.y; m.z += v.z; m.w += v.w;
    }
    const float inv = 1.0f / 16.0f;
    ushort4 sv; sv.x = f2bf(s.x); sv.y = f2bf(s.y); sv.z = f2bf(s.z); sv.w = f2bf(s.w);
    ushort4 mv; mv.x = f2bf(m.x * inv); mv.y = f2bf(m.y * inv);
    mv.z = f2bf(m.z * inv); mv.w = f2bf(m.w * inv);

    unsigned short* row = comb + (size_t)b * KDIM;
    *reinterpret_cast<ushort4*>(row + lane * 4) = sv;
    *reinterpret_cast<ushort4*>(row + D + lane * 4) = mv;
}

// --- kernel 3: out[m][n] = relu(sum_k Wc[m][k] * comb[n][k]), f32 out ---
#define BM 128
#define BN 128
#define BK 32
#define LDK 40   // padded LDS row (elems); 80B stride, 16B-aligned

__global__ __launch_bounds__(256) void gemm_kernel(
        const unsigned short* __restrict__ Wc,    // [512][512] bf16
        const unsigned short* __restrict__ Cb,    // [20000][512] bf16
        float* __restrict__ out) {                // [512][20000] f32
    __shared__ __align__(16) unsigned short As[BM * LDK];
    __shared__ __align__(16) unsigned short Bs[BN * LDK];

    int tid = threadIdx.x;
    int lane = tid & 63;
    int wid = tid >> 6;
    int wm = wid >> 1, wn = wid & 1;              // 2x2 wave grid, 64x64 each
    int mBase = blockIdx.y * BM;
    int nBase = blockIdx.x * BN;

    f32x4 acc[4][4] = {};

    int srow = tid >> 2;                          // 0..63
    int scol = (tid & 3) * 8;                     // 0,8,16,24

    for (int k0 = 0; k0 < KDIM; k0 += BK) {
        #pragma unroll
        for (int h = 0; h < 2; ++h) {
            int r = srow + h * 64;
            uint4 va = *reinterpret_cast<const uint4*>(
                Wc + (size_t)(mBase + r) * KDIM + k0 + scol);
            *reinterpret_cast<uint4*>(&As[r * LDK + scol]) = va;
            int gb = nBase + r;
            uint4 vb;
            if (gb < NB) vb = *reinterpret_cast<const uint4*>(
                    Cb + (size_t)gb * KDIM + k0 + scol);
            else { vb.x = 0; vb.y = 0; vb.z = 0; vb.w = 0; }
            *reinterpret_cast<uint4*>(&Bs[r * LDK + scol]) = vb;
        }
        __syncthreads();

        int kq = (lane >> 4) * 8;
        int rl = lane & 15;
        bf16x8 af[4], bfr[4];
        #pragma unroll
        for (int i = 0; i < 4; ++i) {
            af[i]  = *reinterpret_cast<const bf16x8*>(&As[(wm * 64 + i * 16 + rl) * LDK + kq]);
            bfr[i] = *reinterpret_cast<const bf16x8*>(&Bs[(wn * 64 + i * 16 + rl) * LDK + kq]);
        }
        #pragma unroll
        for (int i = 0; i < 4; ++i)
            #pragma unroll
            for (int j = 0; j < 4; ++j)
                acc[i][j] = __builtin_amdgcn_mfma_f32_16x16x32_bf16(
                    af[i], bfr[j], acc[i][j], 0, 0, 0);
        __syncthreads();
    }

    int col = lane & 15;
    int rq = (lane >> 4) * 4;
    #pragma unroll
    for (int i = 0; i < 4; ++i) {
        #pragma unroll
        for (int j = 0; j < 4; ++j) {
            int n = nBase + wn * 64 + j * 16 + col;
            if (n < NB) {
                int mRow = mBase + wm * 64 + i * 16 + rq;
                #pragma unroll
                for (int r = 0; r < 4; ++r) {
                    float v = acc[i][j][r];
                    out[(size_t)(mRow + r) * NB + n] = v > 0.f ? v : 0.f;
                }
            }
        }
    }
}

extern "C" void kernel_launch(void* const* d_in, const int* in_sizes, int n_in,
                              void* d_out, int out_size, void* d_ws, size_t ws_size,
                              hipStream_t stream) {
    const int*   nodes = (const int*)d_in[0];
    const int*   neigh = (const int*)d_in[1];
    const float* feat  = (const float*)d_in[2];
    const float* W1    = (const float*)d_in[3];
    const float* W2    = (const float*)d_in[4];
    float* out = (float*)d_out;

    // ws layout: Wc (512KB) | featbf (51.2MB) | comb (20.48MB)
    const size_t WC_BYTES   = (size_t)MDIM * KDIM * 2;            // 524288
    const size_t FB_BYTES   = (size_t)NTOT * D * 2;               // 51200000
    const size_t COMB_BYTES = (size_t)NB * KDIM * 2;              // 20480000
    unsigned short* Wc = (unsigned short*)d_ws;

    convW_kernel<<<256, 256, 0, stream>>>(W1, W2, Wc);

    if (ws_size >= WC_BYTES + FB_BYTES + COMB_BYTES) {
        unsigned short* fb   = (unsigned short*)((char*)d_ws + WC_BYTES);
        unsigned short* comb = (unsigned short*)((char*)d_ws + WC_BYTES + FB_BYTES);
        conv_feat_kernel<<<2048, 256, 0, stream>>>(feat, fb);
        agg_bf16_kernel<<<NB / 4, 256, 0, stream>>>(nodes, neigh, fb, comb);
        gemm_kernel<<<dim3((NB + BN - 1) / BN, MDIM / BM), 256, 0, stream>>>(Wc, comb, out);
    } else {
        unsigned short* comb = (unsigned short*)((char*)d_ws + WC_BYTES);
        agg_kernel<<<NB / 4, 256, 0, stream>>>(nodes, neigh, feat, comb);
        gemm_kernel<<<dim3((NB + BN - 1) / BN, MDIM / BM), 256, 0, stream>>>(Wc, comb, out);
    }
}